// Round 2
// baseline (722.110 us; speedup 1.0000x reference)
//
#include <hip/hip_runtime.h>
#include <hip/hip_bf16.h>

// Problem constants
#define BB 4
#define TT 2048
#define CC 1024
#define HH 16
#define DD 64
#define FF 4096
#define MM (BB*TT)   // 8192

typedef __attribute__((ext_vector_type(4))) float  f32x4;
typedef __attribute__((ext_vector_type(8))) __bf16 bf16x8v;
typedef __attribute__((ext_vector_type(4))) short  s16x4;
typedef __attribute__((ext_vector_type(8))) short  s16x8;
typedef __attribute__((ext_vector_type(4))) unsigned short u16x4;

__device__ inline unsigned short bf16bits(float f){
  __hip_bfloat16 h = __float2bfloat16(f);
  return __builtin_bit_cast(unsigned short, h);
}
__device__ inline bf16x8v as_bf16x8(s16x8 s){ return __builtin_bit_cast(bf16x8v, s); }

__device__ inline void gload_lds16(const void* g, void* l){
  __builtin_amdgcn_global_load_lds((const __attribute__((address_space(1))) void*)g,
                                   (__attribute__((address_space(3))) void*)l, 16, 0, 0);
}

// ---------------- weight transpose-cast: in [K][N] f32 -> out [N][K] bf16 ----------------
__global__ __launch_bounds__(256) void transpose_cast(const float* __restrict__ in,
                                                      unsigned short* __restrict__ out,
                                                      int K, int N){
  __shared__ float tile[32][33];
  int n0 = blockIdx.x*32, k0 = blockIdx.y*32;
  int tx = threadIdx.x, ty = threadIdx.y;
#pragma unroll
  for (int i=0;i<32;i+=8) tile[ty+i][tx] = in[(size_t)(k0+ty+i)*N + n0+tx];
  __syncthreads();
#pragma unroll
  for (int i=0;i<32;i+=8)
    out[(size_t)(n0+ty+i)*K + k0+tx] = bf16bits(tile[tx][ty+i]);
}

// wq/wk/wv: [H][C][D] f32 -> wqkvt [3*C][C] bf16, row n = sel*1024 + h*64 + d, col k = c
__global__ __launch_bounds__(256) void tcast_qkv(const float* __restrict__ wq,
                                                 const float* __restrict__ wk,
                                                 const float* __restrict__ wv,
                                                 unsigned short* __restrict__ out){
  int z = blockIdx.z; int sel = z>>4; int h = z&15;
  const float* w = (sel==0)?wq:((sel==1)?wk:wv);
  const float* in = w + (size_t)h*CC*DD;                 // [C][64]
  unsigned short* o = out + (size_t)(sel*1024 + h*64)*CC; // [64][C]
  __shared__ float tile[32][33];
  int d0 = blockIdx.x*32, c0 = blockIdx.y*32;
  int tx = threadIdx.x, ty = threadIdx.y;
#pragma unroll
  for (int i=0;i<32;i+=8) tile[ty+i][tx] = in[(size_t)(c0+ty+i)*DD + d0+tx];
  __syncthreads();
#pragma unroll
  for (int i=0;i<32;i+=8)
    o[(size_t)(d0+ty+i)*CC + c0+tx] = bf16bits(tile[tx][ty+i]);
}

// ---------------- LayerNorm: per-row (1024), out bf16 ----------------
__global__ __launch_bounds__(256) void ln_kernel(const float* __restrict__ x,
                                                 const float* __restrict__ sc,
                                                 const float* __restrict__ bi,
                                                 unsigned short* __restrict__ out){
  __shared__ float red[4];
  const int row = blockIdx.x, tid = threadIdx.x;
  const float4 xv = ((const float4*)(x + (size_t)row*CC))[tid];
  float s = xv.x + xv.y + xv.z + xv.w;
#pragma unroll
  for (int m=32;m>=1;m>>=1) s += __shfl_xor(s, m);
  if ((tid&63)==0) red[tid>>6] = s;
  __syncthreads();
  s = red[0]+red[1]+red[2]+red[3];
  const float mu = s * (1.0f/1024.0f);
  const float d0=xv.x-mu, d1=xv.y-mu, d2=xv.z-mu, d3=xv.w-mu;
  float sq = d0*d0 + d1*d1 + d2*d2 + d3*d3;
  __syncthreads();
#pragma unroll
  for (int m=32;m>=1;m>>=1) sq += __shfl_xor(sq, m);
  if ((tid&63)==0) red[tid>>6] = sq;
  __syncthreads();
  sq = red[0]+red[1]+red[2]+red[3];
  const float inv = rsqrtf(sq*(1.0f/1024.0f) + 1e-6f);
  const float4 scv = ((const float4*)sc)[tid];
  const float4 biv = ((const float4*)bi)[tid];
  u16x4 o;
  o[0] = bf16bits(d0*inv*scv.x + biv.x);
  o[1] = bf16bits(d1*inv*scv.y + biv.y);
  o[2] = bf16bits(d2*inv*scv.z + biv.z);
  o[3] = bf16bits(d3*inv*scv.w + biv.w);
  ((u16x4*)(out + (size_t)row*CC))[tid] = o;
}

// ---------------- GEMM: C[m][n] = sum_k A[m][k]*Bt[n][k], A/Bt bf16 row-major ----------------
// EPI: 0 = bf16 out; 1 = f32 out + bias + resid; 2 = bf16 relu(acc+bias); 3 = f32 out + bias + resid
template<int EPI>
__global__ __launch_bounds__(256) void gemm_bf16(
    const unsigned short* __restrict__ A, const unsigned short* __restrict__ Bt,
    void* __restrict__ Cout, const float* __restrict__ bias,
    const float* __restrict__ resid, int M, int N, int K)
{
  __shared__ unsigned short smem[8192]; // A tile [128][32] at 0, B tile [128][32] at 4096
  const int tid = threadIdx.x;
  const int lane = tid & 63, w = tid >> 6;
  const int m0 = blockIdx.y * 128, n0 = blockIdx.x * 128;
  const int wr = w >> 1, wc = w & 1;
  const int g = lane >> 4, q = lane & 15;
  f32x4 acc[4][4] = {};

  for (int k0 = 0; k0 < K; k0 += 32){
    __syncthreads();
#pragma unroll
    for (int i=0;i<2;i++){
      const int chunk = w*2 + i;
      const int row = chunk*16 + (lane>>2);
      const int ce  = (lane&3)*8;   // element col offset
      gload_lds16(A  + (size_t)(m0+row)*K + k0 + ce, (void*)&smem[chunk*512]);
      gload_lds16(Bt + (size_t)(n0+row)*K + k0 + ce, (void*)&smem[4096 + chunk*512]);
    }
    __syncthreads();
    bf16x8v af[4], bfr[4];
#pragma unroll
    for (int m=0;m<4;m++) af[m]  = as_bf16x8(*(const s16x8*)&smem[(wr*64 + m*16 + q)*32 + g*8]);
#pragma unroll
    for (int n=0;n<4;n++) bfr[n] = as_bf16x8(*(const s16x8*)&smem[4096 + (wc*64 + n*16 + q)*32 + g*8]);
#pragma unroll
    for (int m=0;m<4;m++)
#pragma unroll
      for (int n=0;n<4;n++)
        acc[m][n] = __builtin_amdgcn_mfma_f32_16x16x32_bf16(af[m], bfr[n], acc[m][n], 0,0,0);
  }

#pragma unroll
  for (int m=0;m<4;m++)
#pragma unroll
    for (int n=0;n<4;n++){
      const int col = n0 + wc*64 + n*16 + q;
#pragma unroll
      for (int r=0;r<4;r++){
        const int row = m0 + wr*64 + m*16 + g*4 + r;
        float v = acc[m][n][r];
        if (EPI==0){
          ((unsigned short*)Cout)[(size_t)row*N + col] = bf16bits(v);
        } else if (EPI==1 || EPI==3){
          v += bias[col] + resid[(size_t)row*N + col];
          ((float*)Cout)[(size_t)row*N + col] = v;
        } else { // EPI==2
          v += bias[col];
          v = fmaxf(v, 0.0f);
          ((unsigned short*)Cout)[(size_t)row*N + col] = bf16bits(v);
        }
      }
    }
}

// ---------------- causal flash attention ----------------
// qkv: [M][3072] bf16 (q: n=h*64+d, k: 1024+h*64+d, v: 2048+h*64+d), out: [M][1024] bf16
__global__ __launch_bounds__(64) void attn_kernel(const unsigned short* __restrict__ qkv,
                                                  unsigned short* __restrict__ outc){
  const int lane = threadIdx.x;
  const int q0 = blockIdx.x*16;
  const int bh = blockIdx.y; const int b = bh>>4, h = bh&15;
  const int g = lane>>4, qq = lane&15;
  const size_t base = (size_t)(b*TT)*3072;
  const int qcol = h*64, kcol = 1024 + h*64, vcol = 2048 + h*64;

  // Q fragments (B-operand of S^T mfma): col=q=lane&15, k = d = kk*32 + g*8 + j
  s16x8 qf0, qf1;
  {
    const unsigned short* qp = qkv + base + (size_t)(q0+qq)*3072 + qcol + g*8;
    qf0 = *(const s16x8*)(qp);
    qf1 = *(const s16x8*)(qp + 32);
  }

  float m_i = -INFINITY, l_i = 0.0f;
  f32x4 ot[4] = {};   // O^T acc: row = d = mb*16 + g*4 + r, col = q

  for (int s0 = 0; s0 <= q0; s0 += 16){
    // K tile fragments (A-operand): row=key=lane&15, k = d
    const unsigned short* kp = qkv + base + (size_t)(s0+qq)*3072 + kcol + g*8;
    s16x8 kf0 = *(const s16x8*)(kp);
    s16x8 kf1 = *(const s16x8*)(kp + 32);
    f32x4 st = {};
    st = __builtin_amdgcn_mfma_f32_16x16x32_bf16(as_bf16x8(kf0), as_bf16x8(qf0), st, 0,0,0);
    st = __builtin_amdgcn_mfma_f32_16x16x32_bf16(as_bf16x8(kf1), as_bf16x8(qf1), st, 0,0,0);
    // st[r] = S^T[key = s0 + g*4 + r][q = q0 + qq]
    float sv[4]; float pm = -INFINITY;
#pragma unroll
    for (int r=0;r<4;r++){
      const int s_abs = s0 + g*4 + r;
      float v = st[r] * 0.03125f;              // scale = C^-0.5 = 1/32 (quirk)
      if (s_abs > q0 + qq) v = -INFINITY;      // causal
      sv[r] = v;
      pm = fmaxf(pm, v);
    }
    pm = fmaxf(pm, __shfl_xor(pm, 16));
    pm = fmaxf(pm, __shfl_xor(pm, 32));
    const float m_new = fmaxf(m_i, pm);
    const float alpha = __expf(m_i - m_new);
    float p[4]; float ps = 0.0f;
#pragma unroll
    for (int r=0;r<4;r++){ p[r] = __expf(sv[r] - m_new); ps += p[r]; }
    ps += __shfl_xor(ps, 16);
    ps += __shfl_xor(ps, 32);
    l_i = l_i*alpha + ps;
    s16x4 pb;
#pragma unroll
    for (int r=0;r<4;r++) pb[r] = (short)bf16bits(p[r]);
#pragma unroll
    for (int mb=0;mb<4;mb++){
      ot[mb] *= alpha;
      s16x4 vf;
#pragma unroll
      for (int j=0;j<4;j++){
        const int s_abs = s0 + g*4 + j;
        vf[j] = (short)qkv[base + (size_t)s_abs*3072 + vcol + mb*16 + qq];
      }
      // A = V^T block (row=d, k=s), B = P^T (k=s, col=q)
      ot[mb] = __builtin_amdgcn_mfma_f32_16x16x16bf16_1k(vf, pb, ot[mb], 0,0,0);
    }
    m_i = m_new;
  }

  const float inv = 1.0f / l_i;
#pragma unroll
  for (int mb=0;mb<4;mb++){
    u16x4 o;
#pragma unroll
    for (int r=0;r<4;r++) o[r] = bf16bits(ot[mb][r] * inv);
    *(u16x4*)&outc[(size_t)(b*TT + q0 + qq)*1024 + h*64 + mb*16 + g*4] = o;
  }
}

// ---------------- host ----------------
extern "C" void kernel_launch(void* const* d_in, const int* in_sizes, int n_in,
                              void* d_out, int out_size, void* d_ws, size_t ws_size,
                              hipStream_t stream)
{
  const float* x   = (const float*)d_in[0];
  const float* wq  = (const float*)d_in[1];
  const float* wk  = (const float*)d_in[2];
  const float* wv  = (const float*)d_in[3];
  const float* wpr = (const float*)d_in[4];
  const float* bpr = (const float*)d_in[5];
  const float* l1s = (const float*)d_in[6];
  const float* l1b = (const float*)d_in[7];
  const float* l2s = (const float*)d_in[8];
  const float* l2b = (const float*)d_in[9];
  const float* w1  = (const float*)d_in[10];
  const float* b1  = (const float*)d_in[11];
  const float* w2  = (const float*)d_in[12];
  const float* b2  = (const float*)d_in[13];
  float* out = (float*)d_out;

  char* ws = (char*)d_ws;
  unsigned short* qkv   = (unsigned short*)(ws + 0);          // 8192*3072*2 = 50331648
  unsigned short* hb    = (unsigned short*)(ws + 50331648);   // 16777216
  unsigned short* attnc = (unsigned short*)(ws + 67108864);   // 16777216
  float*          x1    = (float*)        (ws + 83886080);    // 33554432
  unsigned short* h2    = attnc;                              // reuse (attn dead after proj)
  unsigned short* act   = (unsigned short*)(ws + 0);          // reuse qkv+hb (67108864)
  unsigned short* wqkvt = (unsigned short*)(ws + 117440512);  // 6291456
  unsigned short* wprt  = (unsigned short*)(ws + 123731968);  // 2097152
  unsigned short* w1t   = (unsigned short*)(ws + 125829120);  // 8388608
  unsigned short* w2t   = (unsigned short*)(ws + 134217728);  // 8388608 (end 142606336)

  tcast_qkv<<<dim3(2,32,48), dim3(32,8), 0, stream>>>(wq, wk, wv, wqkvt);
  transpose_cast<<<dim3(32,32),  dim3(32,8), 0, stream>>>(wpr, wprt, 1024, 1024);
  transpose_cast<<<dim3(128,32), dim3(32,8), 0, stream>>>(w1,  w1t,  1024, 4096);
  transpose_cast<<<dim3(32,128), dim3(32,8), 0, stream>>>(w2,  w2t,  4096, 1024);

  ln_kernel<<<MM, 256, 0, stream>>>(x, l1s, l1b, hb);
  gemm_bf16<0><<<dim3(24,64), 256, 0, stream>>>(hb, wqkvt, qkv, nullptr, nullptr, MM, 3072, 1024);
  attn_kernel<<<dim3(TT/16, BB*HH), 64, 0, stream>>>(qkv, attnc);
  gemm_bf16<1><<<dim3(8,64), 256, 0, stream>>>(attnc, wprt, x1, bpr, x, MM, 1024, 1024);
  ln_kernel<<<MM, 256, 0, stream>>>(x1, l2s, l2b, h2);
  gemm_bf16<2><<<dim3(32,64), 256, 0, stream>>>(h2, w1t, act, b1, nullptr, MM, 4096, 1024);
  gemm_bf16<3><<<dim3(8,64), 256, 0, stream>>>(act, w2t, out, b2, x1, MM, 1024, 4096);
}